// Round 8
// baseline (250.322 us; speedup 1.0000x reference)
//
#include <hip/hip_runtime.h>
#include <math.h>

// GraphSAGE mean, 2 layers. F_IN=5, F_HID=5, F_OUT=10.
// Pipeline: init_cursors | partition (dst>>6 radix, CHUNK=4096, 1024thr) |
// sortagg1 (64-node buckets, register-staged counting sort + fused layer-1) |
// layer2 (8 lanes/node gather, 512thr).
// R7 lesson: grid quantization (blocks/CU vs resident slots) cost ~30% in the
// two big kernels; NB=1563 / CHUNK=4096 makes rounds ~= ideal.

#define F_IN  5
#define F_HID 5
#define F_OUT 10

#define NBSHIFT 6                 // nodes per bucket = 64
#define NPB     (1 << NBSHIFT)    // 64
#define MAXNB   1664              // partition LDS array bound (actual NB=1563)
#define PBLK    1024              // partition block size
#define CHUNK   4096              // edges per partition block
#define BSTRIDE 4608              // bucket stride: mean 4096 + 8 sigma; = 9*512
#define SBLK    512               // sortagg1 block size (8 lanes/node * 64)
#define SPT     9                 // staged entries/thread = BSTRIDE/SBLK
#define LPN2    8                 // lanes per node in layer2
#define LBLK    512               // layer2 block size

// ---- init per-bucket write cursors to region starts ----
__global__ void init_cursors(int* __restrict__ bcursor, int NB) {
    int t = blockIdx.x * blockDim.x + threadIdx.x;
    if (t < NB) bcursor[t] = t * BSTRIDE;
}

// ---- partition edges into padded bucket regions (coalesced run writes) ----
__global__ void partition(const int* __restrict__ src, const int* __restrict__ dst,
                          int* __restrict__ bcursor, int* __restrict__ packed,
                          int E, int NB) {
    __shared__ int h[MAXNB], excl[MAXNB], adj[MAXNB];
    __shared__ int scanTmp[PBLK];
    __shared__ int buf[CHUNK];
    __shared__ unsigned char dlow[CHUNK];
    int t = threadIdx.x;
    for (int i = t; i < MAXNB; i += PBLK) h[i] = 0;
    __syncthreads();
    int base = blockIdx.x * CHUNK;
    int end  = min(base + CHUNK, E);
    for (int i = base + t; i < end; i += PBLK)
        atomicAdd(&h[dst[i] >> NBSHIFT], 1);
    __syncthreads();
    // exclusive scan of h[0..NB) (NB <= 2*PBLK): 2 elems per thread
    int a0 = h[2 * t];
    int a1 = h[2 * t + 1];
    scanTmp[t] = a0 + a1;
    __syncthreads();
    for (int off = 1; off < PBLK; off <<= 1) {
        int v = (t >= off) ? scanTmp[t - off] : 0;
        __syncthreads();
        scanTmp[t] += v;
        __syncthreads();
    }
    int pairExcl = (t == 0) ? 0 : scanTmp[t - 1];
    excl[2 * t]     = pairExcl;
    excl[2 * t + 1] = pairExcl + a0;
    __syncthreads();
    // reserve global space per bucket; adj[b] = goff - excl_orig[b]
    for (int i = t; i < NB; i += PBLK) {
        int cb = h[i];
        int go = cb ? atomicAdd(&bcursor[i], cb) : 0;
        adj[i] = go - excl[i];
    }
    __syncthreads();
    // scatter chunk into LDS, bucket-grouped (excl doubles as cursor)
    for (int i = base + t; i < end; i += PBLK) {
        int d = dst[i];
        int b = d >> NBSHIFT;
        int p = atomicAdd(&excl[b], 1);
        buf[p]  = src[i] | (b << 17);          // b < 2048 -> bits 17..27
        dlow[p] = (unsigned char)(d & (NPB - 1));
    }
    __syncthreads();
    // write runs out (consecutive p -> same bucket -> coalesced)
    int cnt = end - base;
    for (int p = t; p < cnt; p += PBLK) {
        int e = buf[p];
        int b = e >> 17;
        packed[adj[b] + p] = (e & 0x1FFFF) | ((int)dlow[p] << 17);
    }
}

__device__ __forceinline__ float sigmoidf(float v) {
    return 1.0f / (1.0f + __expf(-v));
}

// ---- fused: per-bucket counting sort (register-staged) + layer-1 ----
// Writes sorted eidx back (in place), starts[], degs[], hp rows of 5.
__global__ void sortagg1(const float* __restrict__ x, int* __restrict__ packed,
                         const int* __restrict__ bcursor,
                         const float* __restrict__ Ws, const float* __restrict__ Wn,
                         const float* __restrict__ bias,
                         float* __restrict__ hp, int* __restrict__ starts,
                         int* __restrict__ degs, int N) {
    __shared__ int buf[BSTRIDE];
    __shared__ int nhist[NPB], ncur[NPB], nst[NPB];
    int b = blockIdx.x, t = threadIdx.x;
    int s0  = b * BSTRIDE;
    int cnt = min(bcursor[b] - s0, BSTRIDE);
    if (t < NPB) nhist[t] = 0;
    __syncthreads();
    // phase 1: stage packed entries in registers + LDS histogram of dst-low
    int myv[SPT];
    #pragma unroll
    for (int j = 0; j < SPT; ++j) {
        int i = t + j * SBLK;
        if (i < cnt) {
            int e = packed[s0 + i];
            myv[j] = e;
            atomicAdd(&nhist[(e >> 17) & (NPB - 1)], 1);
        }
    }
    __syncthreads();
    // scan 64 bins (first 64 threads; all hit barriers)
    int v = (t < NPB) ? nhist[t] : 0;
    if (t < NPB) ncur[t] = v;
    __syncthreads();
    for (int off = 1; off < NPB; off <<= 1) {
        int u = (t < NPB && t >= off) ? ncur[t - off] : 0;
        __syncthreads();
        if (t < NPB) ncur[t] += u;
        __syncthreads();
    }
    if (t < NPB) {
        int ex = ncur[t] - v;
        nst[t]  = ex;
        ncur[t] = ex;
        int node = (b << NBSHIFT) + t;
        if (node < N) { starts[node] = s0 + ex; degs[node] = v; }
    }
    __syncthreads();
    // phase 2: scatter-sort from registers into LDS
    #pragma unroll
    for (int j = 0; j < SPT; ++j) {
        int i = t + j * SBLK;
        if (i < cnt) {
            int e = myv[j];
            int p = atomicAdd(&ncur[(e >> 17) & (NPB - 1)], 1);
            buf[p] = e;
        }
    }
    __syncthreads();
    // phase 3: write sorted eidx back for layer2
    for (int i = t; i < cnt; i += SBLK)
        packed[s0 + i] = buf[i] & 0x1FFFF;
    // phase 4: layer-1 aggregation from LDS, 8 lanes per node
    int sub = t & 7, ln = t >> 3;          // ln in [0,64)
    int node = (b << NBSHIFT) + ln;
    float a0 = 0, a1 = 0, a2 = 0, a3 = 0, a4 = 0;
    int dg = 0;
    if (node < N) {
        int st = nst[ln];
        dg = nhist[ln];
        for (int k = sub; k < dg; k += 8) {
            int u = buf[st + k] & 0x1FFFF;
            const float* fr = x + (size_t)u * 5;
            float4 a = *(const float4*)fr;   // 4B-aligned unaligned-vec ok
            float  e4 = fr[4];
            a0 += a.x; a1 += a.y; a2 += a.z; a3 += a.w; a4 += e4;
        }
    }
    #pragma unroll
    for (int off = 4; off > 0; off >>= 1) {
        a0 += __shfl_down(a0, off, 8);
        a1 += __shfl_down(a1, off, 8);
        a2 += __shfl_down(a2, off, 8);
        a3 += __shfl_down(a3, off, 8);
        a4 += __shfl_down(a4, off, 8);
    }
    if (sub != 0 || node >= N) return;
    float rd = 1.0f / fmaxf((float)dg, 1.0f);
    float ni[F_IN] = { a0 * rd, a1 * rd, a2 * rd, a3 * rd, a4 * rd };
    float xi[F_IN];
    const float* xr = x + (size_t)node * 5;
    #pragma unroll
    for (int f = 0; f < F_IN; ++f) xi[f] = xr[f];
    #pragma unroll
    for (int j = 0; j < F_HID; ++j) {
        float acc = bias[j];
        #pragma unroll
        for (int f = 0; f < F_IN; ++f)
            acc += xi[f] * Ws[f * F_HID + j] + ni[f] * Wn[f * F_HID + j];
        hp[(size_t)node * 5 + j] = sigmoidf(acc);
    }
}

// ---- layer 2: 8 lanes/node edge-parallel gather + reduce + matmul ----
__global__ void layer2(const float* __restrict__ hp, const int* __restrict__ eidx,
                       const int* __restrict__ starts, const int* __restrict__ degs,
                       const float* __restrict__ Ws, const float* __restrict__ Wn,
                       const float* __restrict__ b,
                       float* __restrict__ out, int N) {
    int tid = blockIdx.x * blockDim.x + threadIdx.x;
    int v   = tid >> 3;
    int sub = threadIdx.x & (LPN2 - 1);
    if (v >= N) return;
    int st = starts[v], dg = degs[v];
    float s0 = 0, s1 = 0, s2 = 0, s3 = 0, s4 = 0;
    for (int k = sub; k < dg; k += LPN2) {
        int u = eidx[st + k];
        const float* fr = hp + (size_t)u * 5;
        float4 a = *(const float4*)fr;
        float a4 = fr[4];
        s0 += a.x; s1 += a.y; s2 += a.z; s3 += a.w; s4 += a4;
    }
    #pragma unroll
    for (int off = LPN2 / 2; off > 0; off >>= 1) {
        s0 += __shfl_down(s0, off, LPN2);
        s1 += __shfl_down(s1, off, LPN2);
        s2 += __shfl_down(s2, off, LPN2);
        s3 += __shfl_down(s3, off, LPN2);
        s4 += __shfl_down(s4, off, LPN2);
    }
    if (sub != 0) return;
    float rd = 1.0f / fmaxf((float)dg, 1.0f);
    float ni[F_HID] = { s0 * rd, s1 * rd, s2 * rd, s3 * rd, s4 * rd };
    float hi[F_HID];
    const float* hr = hp + (size_t)v * 5;
    #pragma unroll
    for (int f = 0; f < F_HID; ++f) hi[f] = hr[f];
    #pragma unroll
    for (int j = 0; j < F_OUT; ++j) {
        float acc = b[j];
        #pragma unroll
        for (int f = 0; f < F_HID; ++f)
            acc += hi[f] * Ws[f * F_OUT + j] + ni[f] * Wn[f * F_OUT + j];
        out[(size_t)v * F_OUT + j] = sigmoidf(acc);
    }
}

extern "C" void kernel_launch(void* const* d_in, const int* in_sizes, int n_in,
                              void* d_out, int out_size, void* d_ws, size_t ws_size,
                              hipStream_t stream) {
    const float* x   = (const float*)d_in[0];
    const int*   src = (const int*)d_in[1];
    const int*   dst = (const int*)d_in[2];
    const float* Ws1 = (const float*)d_in[3];
    const float* Wn1 = (const float*)d_in[4];
    const float* b1  = (const float*)d_in[5];
    const float* Ws2 = (const float*)d_in[6];
    const float* Wn2 = (const float*)d_in[7];
    const float* b2  = (const float*)d_in[8];
    float* out = (float*)d_out;

    const int N  = in_sizes[0] / F_IN;        // 100000
    const int E  = in_sizes[1];               // 6400000
    const int NB = (N + NPB - 1) >> NBSHIFT;  // 1563

    // workspace (4B units):
    // bcursor[2048] | starts[N] | degs[N] | packed[NB*BSTRIDE] | hp[5N]
    int*   bcursor = (int*)d_ws;
    int*   starts  = bcursor + 2048;
    int*   degs    = starts + N;
    int*   packed  = degs + N;
    float* hp      = (float*)(packed + (size_t)NB * BSTRIDE);

    const int ablocks = (E + CHUNK - 1) / CHUNK;              // 1563
    const int lgrid   = ((size_t)N * LPN2 + LBLK - 1) / LBLK; // 1563

    init_cursors<<<2, 1024, 0, stream>>>(bcursor, NB);
    partition<<<ablocks, PBLK, 0, stream>>>(src, dst, bcursor, packed, E, NB);
    sortagg1<<<NB, SBLK, 0, stream>>>(x, packed, bcursor, Ws1, Wn1, b1,
                                      hp, starts, degs, N);
    layer2<<<lgrid, LBLK, 0, stream>>>(hp, packed, starts, degs, Ws2, Wn2, b2, out, N);
}

// Round 9
// 232.499 us; speedup vs baseline: 1.0767x; 1.0767x over previous
//
#include <hip/hip_runtime.h>
#include <math.h>

// GraphSAGE mean, 2 layers. F_IN=5, F_HID=5, F_OUT=10.
// Pipeline: init_cursors | partition (dst>>7 radix, CHUNK=8192, 1024thr) |
// sortagg1 (128-node buckets, register-staged counting sort + fused layer-1) |
// layer2 (8 lanes/node gather, 256thr).
// R8 lesson: partition write-run length = CHUNK/NB must stay >= ~10 or
// partial-line writebacks double WRITE_SIZE and cost ~20 us. R7 geometry is
// the sweet spot; register staging in sortagg1 kills the 2nd packed read.

#define F_IN  5
#define F_HID 5
#define F_OUT 10

#define NBSHIFT 7                 // nodes per bucket = 128
#define NPB     (1 << NBSHIFT)    // 128
#define PBLK    1024              // partition block size
#define CHUNK   8192              // edges per partition block -> run len ~10.5
#define BSTRIDE 9216              // bucket stride: mean 8184 + ~11 sigma; 18*512
#define SBLK    512               // sortagg1 block size (4 lanes/node * 128)
#define SPT     18                // staged entries/thread = BSTRIDE/SBLK
#define LPN2    8                 // lanes per node in layer2
#define LBLK    256               // layer2 block size

// ---- init per-bucket write cursors to region starts ----
__global__ void init_cursors(int* __restrict__ bcursor, int NB) {
    int t = blockIdx.x * blockDim.x + threadIdx.x;
    if (t < NB) bcursor[t] = t * BSTRIDE;
}

// ---- partition edges into padded bucket regions (coalesced run writes) ----
__global__ void partition(const int* __restrict__ src, const int* __restrict__ dst,
                          int* __restrict__ bcursor, int* __restrict__ packed,
                          int E, int NB) {
    __shared__ int h[PBLK], s[PBLK], excl[PBLK], adj[PBLK];
    __shared__ int buf[CHUNK];
    __shared__ unsigned char dlow[CHUNK];
    int t = threadIdx.x;
    h[t] = 0;
    __syncthreads();
    int base = blockIdx.x * CHUNK;
    int end  = min(base + CHUNK, E);
    for (int i = base + t; i < end; i += PBLK)
        atomicAdd(&h[dst[i] >> NBSHIFT], 1);
    __syncthreads();
    // inclusive scan of h[0..PBLK), one elem per thread (NB <= PBLK)
    s[t] = h[t];
    __syncthreads();
    for (int off = 1; off < PBLK; off <<= 1) {
        int v = (t >= off) ? s[t - off] : 0;
        __syncthreads();
        s[t] += v;
        __syncthreads();
    }
    excl[t] = s[t] - h[t];
    __syncthreads();
    // reserve global space per bucket; adj[b] = goff - excl_orig[b]
    if (t < NB) {
        int cb = h[t];
        int go = cb ? atomicAdd(&bcursor[t], cb) : 0;
        adj[t] = go - excl[t];
    }
    __syncthreads();
    // scatter chunk into LDS, bucket-grouped (excl doubles as cursor)
    for (int i = base + t; i < end; i += PBLK) {
        int d = dst[i];
        int b = d >> NBSHIFT;
        int p = atomicAdd(&excl[b], 1);
        buf[p]  = src[i] | (b << 17);          // b < 1024 -> bits 17..26
        dlow[p] = (unsigned char)(d & (NPB - 1));
    }
    __syncthreads();
    // write runs out (consecutive p -> same bucket -> coalesced)
    int cnt = end - base;
    for (int p = t; p < cnt; p += PBLK) {
        int e = buf[p];
        int b = e >> 17;
        packed[adj[b] + p] = (e & 0x1FFFF) | ((int)dlow[p] << 17);
    }
}

__device__ __forceinline__ float sigmoidf(float v) {
    return 1.0f / (1.0f + __expf(-v));
}

// ---- fused: per-bucket counting sort (register-staged) + layer-1 ----
// Writes sorted eidx back (in place), starts[], degs[], hp rows of 5.
__global__ void sortagg1(const float* __restrict__ x, int* __restrict__ packed,
                         const int* __restrict__ bcursor,
                         const float* __restrict__ Ws, const float* __restrict__ Wn,
                         const float* __restrict__ bias,
                         float* __restrict__ hp, int* __restrict__ starts,
                         int* __restrict__ degs, int N) {
    __shared__ int buf[BSTRIDE];
    __shared__ int nhist[NPB], ncur[NPB], nst[NPB];
    int b = blockIdx.x, t = threadIdx.x;
    int s0  = b * BSTRIDE;
    int cnt = min(bcursor[b] - s0, BSTRIDE);
    if (t < NPB) nhist[t] = 0;
    __syncthreads();
    // phase 1: stage packed entries in registers + LDS histogram of dst-low
    int myv[SPT];
    #pragma unroll
    for (int j = 0; j < SPT; ++j) {
        int i = t + j * SBLK;
        if (i < cnt) {
            int e = packed[s0 + i];
            myv[j] = e;
            atomicAdd(&nhist[(e >> 17) & (NPB - 1)], 1);
        }
    }
    __syncthreads();
    // scan 128 bins (first 128 threads; all hit barriers)
    int v = (t < NPB) ? nhist[t] : 0;
    if (t < NPB) ncur[t] = v;
    __syncthreads();
    for (int off = 1; off < NPB; off <<= 1) {
        int u = (t < NPB && t >= off) ? ncur[t - off] : 0;
        __syncthreads();
        if (t < NPB) ncur[t] += u;
        __syncthreads();
    }
    if (t < NPB) {
        int ex = ncur[t] - v;
        nst[t]  = ex;
        ncur[t] = ex;
        int node = (b << NBSHIFT) + t;
        if (node < N) { starts[node] = s0 + ex; degs[node] = v; }
    }
    __syncthreads();
    // phase 2: scatter-sort from registers into LDS
    #pragma unroll
    for (int j = 0; j < SPT; ++j) {
        int i = t + j * SBLK;
        if (i < cnt) {
            int e = myv[j];
            int p = atomicAdd(&ncur[(e >> 17) & (NPB - 1)], 1);
            buf[p] = e;
        }
    }
    __syncthreads();
    // phase 3: write sorted eidx back for layer2
    for (int i = t; i < cnt; i += SBLK)
        packed[s0 + i] = buf[i] & 0x1FFFF;
    // phase 4: layer-1 aggregation from LDS, 4 lanes per node
    int sub = t & 3, ln = t >> 2;          // ln in [0,128)
    int node = (b << NBSHIFT) + ln;
    float a0 = 0, a1 = 0, a2 = 0, a3 = 0, a4 = 0;
    int dg = 0;
    if (node < N) {
        int st = nst[ln];
        dg = nhist[ln];
        for (int k = sub; k < dg; k += 4) {
            int u = buf[st + k] & 0x1FFFF;
            const float* fr = x + (size_t)u * 5;
            float4 a = *(const float4*)fr;   // 4B-aligned unaligned-vec ok
            float  e4 = fr[4];
            a0 += a.x; a1 += a.y; a2 += a.z; a3 += a.w; a4 += e4;
        }
    }
    #pragma unroll
    for (int off = 2; off > 0; off >>= 1) {
        a0 += __shfl_down(a0, off, 4);
        a1 += __shfl_down(a1, off, 4);
        a2 += __shfl_down(a2, off, 4);
        a3 += __shfl_down(a3, off, 4);
        a4 += __shfl_down(a4, off, 4);
    }
    if (sub != 0 || node >= N) return;
    float rd = 1.0f / fmaxf((float)dg, 1.0f);
    float ni[F_IN] = { a0 * rd, a1 * rd, a2 * rd, a3 * rd, a4 * rd };
    float xi[F_IN];
    const float* xr = x + (size_t)node * 5;
    #pragma unroll
    for (int f = 0; f < F_IN; ++f) xi[f] = xr[f];
    #pragma unroll
    for (int j = 0; j < F_HID; ++j) {
        float acc = bias[j];
        #pragma unroll
        for (int f = 0; f < F_IN; ++f)
            acc += xi[f] * Ws[f * F_HID + j] + ni[f] * Wn[f * F_HID + j];
        hp[(size_t)node * 5 + j] = sigmoidf(acc);
    }
}

// ---- layer 2: 8 lanes/node edge-parallel gather + reduce + matmul ----
__global__ void layer2(const float* __restrict__ hp, const int* __restrict__ eidx,
                       const int* __restrict__ starts, const int* __restrict__ degs,
                       const float* __restrict__ Ws, const float* __restrict__ Wn,
                       const float* __restrict__ b,
                       float* __restrict__ out, int N) {
    int tid = blockIdx.x * blockDim.x + threadIdx.x;
    int v   = tid >> 3;
    int sub = threadIdx.x & (LPN2 - 1);
    if (v >= N) return;
    int st = starts[v], dg = degs[v];
    float s0 = 0, s1 = 0, s2 = 0, s3 = 0, s4 = 0;
    for (int k = sub; k < dg; k += LPN2) {
        int u = eidx[st + k];
        const float* fr = hp + (size_t)u * 5;
        float4 a = *(const float4*)fr;
        float a4 = fr[4];
        s0 += a.x; s1 += a.y; s2 += a.z; s3 += a.w; s4 += a4;
    }
    #pragma unroll
    for (int off = LPN2 / 2; off > 0; off >>= 1) {
        s0 += __shfl_down(s0, off, LPN2);
        s1 += __shfl_down(s1, off, LPN2);
        s2 += __shfl_down(s2, off, LPN2);
        s3 += __shfl_down(s3, off, LPN2);
        s4 += __shfl_down(s4, off, LPN2);
    }
    if (sub != 0) return;
    float rd = 1.0f / fmaxf((float)dg, 1.0f);
    float ni[F_HID] = { s0 * rd, s1 * rd, s2 * rd, s3 * rd, s4 * rd };
    float hi[F_HID];
    const float* hr = hp + (size_t)v * 5;
    #pragma unroll
    for (int f = 0; f < F_HID; ++f) hi[f] = hr[f];
    #pragma unroll
    for (int j = 0; j < F_OUT; ++j) {
        float acc = b[j];
        #pragma unroll
        for (int f = 0; f < F_HID; ++f)
            acc += hi[f] * Ws[f * F_OUT + j] + ni[f] * Wn[f * F_OUT + j];
        out[(size_t)v * F_OUT + j] = sigmoidf(acc);
    }
}

extern "C" void kernel_launch(void* const* d_in, const int* in_sizes, int n_in,
                              void* d_out, int out_size, void* d_ws, size_t ws_size,
                              hipStream_t stream) {
    const float* x   = (const float*)d_in[0];
    const int*   src = (const int*)d_in[1];
    const int*   dst = (const int*)d_in[2];
    const float* Ws1 = (const float*)d_in[3];
    const float* Wn1 = (const float*)d_in[4];
    const float* b1  = (const float*)d_in[5];
    const float* Ws2 = (const float*)d_in[6];
    const float* Wn2 = (const float*)d_in[7];
    const float* b2  = (const float*)d_in[8];
    float* out = (float*)d_out;

    const int N  = in_sizes[0] / F_IN;        // 100000
    const int E  = in_sizes[1];               // 6400000
    const int NB = (N + NPB - 1) >> NBSHIFT;  // 782

    // workspace (4B units):
    // bcursor[1024] | starts[N] | degs[N] | packed[NB*BSTRIDE] | hp[5N]
    int*   bcursor = (int*)d_ws;
    int*   starts  = bcursor + 1024;
    int*   degs    = starts + N;
    int*   packed  = degs + N;
    float* hp      = (float*)(packed + (size_t)NB * BSTRIDE);

    const int ablocks = (E + CHUNK - 1) / CHUNK;              // 782
    const int lgrid   = ((size_t)N * LPN2 + LBLK - 1) / LBLK; // 3125

    init_cursors<<<1, 1024, 0, stream>>>(bcursor, NB);
    partition<<<ablocks, PBLK, 0, stream>>>(src, dst, bcursor, packed, E, NB);
    sortagg1<<<NB, SBLK, 0, stream>>>(x, packed, bcursor, Ws1, Wn1, b1,
                                      hp, starts, degs, N);
    layer2<<<lgrid, LBLK, 0, stream>>>(hp, packed, starts, degs, Ws2, Wn2, b2, out, N);
}

// Round 10
// 218.561 us; speedup vs baseline: 1.1453x; 1.0638x over previous
//
#include <hip/hip_runtime.h>
#include <hip/hip_fp16.h>
#include <math.h>

// GraphSAGE mean, 2 layers. F_IN=5, F_HID=5, F_OUT=10.
// R10: cursor-first register staging in both CSR kernels (1 LDS atomic/edge,
// was 2 each); hp stored as half[8] rows so layer2 gathers one dwordx4/edge.
// R8 lesson kept: partition run length CHUNK/NB ~10.5.

#define F_IN  5
#define F_HID 5
#define F_OUT 10

#define NBSHIFT 7                 // nodes per bucket = 128
#define NPB     (1 << NBSHIFT)    // 128
#define PBLK    1024              // partition block size
#define CHUNK   8192              // edges per partition block -> run len ~10.5
#define EPT     8                 // edges per thread in partition
#define BSTRIDE 9216              // bucket stride: mean 8192 + ~11 sigma; 18*512
#define SBLK    512               // sortagg1 block size (4 lanes/node * 128)
#define SPT     18                // staged entries/thread = BSTRIDE/SBLK
#define LPN2    8                 // lanes per node in layer2
#define LBLK    256               // layer2 block size

// ---- init per-bucket write cursors to region starts ----
__global__ void init_cursors(int* __restrict__ bcursor, int NB) {
    int t = blockIdx.x * blockDim.x + threadIdx.x;
    if (t < NB) bcursor[t] = t * BSTRIDE;
}

// ---- partition edges into padded bucket regions (cursor-first, 1 atomic/edge) ----
__global__ void partition(const int* __restrict__ src, const int* __restrict__ dst,
                          int* __restrict__ bcursor, int* __restrict__ packed,
                          int E, int NB) {
    __shared__ int cnt[PBLK], s[PBLK], excl[PBLK], adj[PBLK];
    __shared__ int buf[CHUNK];
    __shared__ unsigned char dlow[CHUNK];
    int t = threadIdx.x;
    cnt[t] = 0;
    __syncthreads();
    int base = blockIdx.x * CHUNK;
    int end  = min(base + CHUNK, E);
    // phase 1: load edges to registers, rank via single LDS cursor atomic
    int esd[EPT];   // src | dlow<<17
    int ebp[EPT];   // b<<14 | p   (p < 8192)
    #pragma unroll
    for (int j = 0; j < EPT; ++j) {
        int i = base + t + j * PBLK;
        if (i < end) {
            int sv = src[i], d = dst[i];
            int b  = d >> NBSHIFT;
            int p  = atomicAdd(&cnt[b], 1);
            esd[j] = sv | ((d & (NPB - 1)) << 17);
            ebp[j] = (b << 14) | p;
        }
    }
    __syncthreads();
    // inclusive scan of cnt[0..PBLK)
    s[t] = cnt[t];
    __syncthreads();
    for (int off = 1; off < PBLK; off <<= 1) {
        int v = (t >= off) ? s[t - off] : 0;
        __syncthreads();
        s[t] += v;
        __syncthreads();
    }
    excl[t] = s[t] - cnt[t];
    __syncthreads();
    // reserve global space per bucket; adj[b] = goff - excl[b]
    if (t < NB) {
        int cb = cnt[t];
        int go = cb ? atomicAdd(&bcursor[t], cb) : 0;
        adj[t] = go - excl[t];
    }
    __syncthreads();
    // phase 2: place from registers into LDS, bucket-grouped (plain writes)
    #pragma unroll
    for (int j = 0; j < EPT; ++j) {
        int i = base + t + j * PBLK;
        if (i < end) {
            int b   = ebp[j] >> 14;
            int pos = excl[b] + (ebp[j] & 0x3FFF);
            buf[pos]  = (esd[j] & 0x1FFFF) | (b << 17);
            dlow[pos] = (unsigned char)(esd[j] >> 17);
        }
    }
    __syncthreads();
    // phase 3: write runs out (consecutive pos -> same bucket -> coalesced)
    int cval = end - base;
    for (int p = t; p < cval; p += PBLK) {
        int e = buf[p];
        int b = e >> 17;
        packed[adj[b] + p] = (e & 0x1FFFF) | ((int)dlow[p] << 17);
    }
}

__device__ __forceinline__ float sigmoidf(float v) {
    return 1.0f / (1.0f + __expf(-v));
}

// ---- fused: per-bucket counting sort (cursor-first, register-staged) + layer-1 ----
// Writes sorted eidx back (in place), starts[], degs[], hp as half[8] rows.
__global__ void __launch_bounds__(SBLK, 8)
sortagg1(const float* __restrict__ x, int* __restrict__ packed,
         const int* __restrict__ bcursor,
         const float* __restrict__ Ws, const float* __restrict__ Wn,
         const float* __restrict__ bias,
         uint4* __restrict__ hp, int* __restrict__ starts,
         int* __restrict__ degs, int N) {
    __shared__ int buf[BSTRIDE];
    __shared__ int ncnt[NPB], nst[NPB];
    int b = blockIdx.x, t = threadIdx.x;
    int s0  = b * BSTRIDE;
    int cnt = min(bcursor[b] - s0, BSTRIDE);
    if (t < NPB) ncnt[t] = 0;
    __syncthreads();
    // phase 1: stage entries in registers, rank via single LDS cursor atomic
    int myv[SPT];
    short myp[SPT];
    #pragma unroll
    for (int j = 0; j < SPT; ++j) {
        int i = t + j * SBLK;
        if (i < cnt) {
            int e = packed[s0 + i];
            myv[j] = e;
            myp[j] = (short)atomicAdd(&ncnt[(e >> 17) & (NPB - 1)], 1);
        }
    }
    __syncthreads();
    // scan 128 bins (first 128 threads; all hit barriers)
    int v = (t < NPB) ? ncnt[t] : 0;
    int run = v;
    __syncthreads();
    if (t < NPB) nst[t] = run;
    __syncthreads();
    for (int off = 1; off < NPB; off <<= 1) {
        int u = (t < NPB && t >= off) ? nst[t - off] : 0;
        __syncthreads();
        if (t < NPB) nst[t] += u;
        __syncthreads();
    }
    if (t < NPB) {
        nst[t] -= v;   // exclusive
        int node = (b << NBSHIFT) + t;
        if (node < N) { starts[node] = s0 + nst[t]; degs[node] = v; }
    }
    __syncthreads();
    // phase 2: place sorted into LDS from registers (plain writes)
    #pragma unroll
    for (int j = 0; j < SPT; ++j) {
        int i = t + j * SBLK;
        if (i < cnt) {
            int e  = myv[j];
            buf[nst[(e >> 17) & (NPB - 1)] + (int)myp[j]] = e;
        }
    }
    __syncthreads();
    // phase 3: write sorted eidx back for layer2
    for (int i = t; i < cnt; i += SBLK)
        packed[s0 + i] = buf[i] & 0x1FFFF;
    // phase 4: layer-1 aggregation from LDS, 4 lanes per node
    int sub = t & 3, ln = t >> 2;          // ln in [0,128)
    int node = (b << NBSHIFT) + ln;
    float a0 = 0, a1 = 0, a2 = 0, a3 = 0, a4 = 0;
    int dg = 0;
    if (node < N) {
        int st = nst[ln];
        dg = ncnt[ln];
        for (int k = sub; k < dg; k += 4) {
            int u = buf[st + k] & 0x1FFFF;
            const float* fr = x + (size_t)u * 5;
            float4 a = *(const float4*)fr;   // 4B-aligned unaligned-vec ok
            float  e4 = fr[4];
            a0 += a.x; a1 += a.y; a2 += a.z; a3 += a.w; a4 += e4;
        }
    }
    #pragma unroll
    for (int off = 2; off > 0; off >>= 1) {
        a0 += __shfl_down(a0, off, 4);
        a1 += __shfl_down(a1, off, 4);
        a2 += __shfl_down(a2, off, 4);
        a3 += __shfl_down(a3, off, 4);
        a4 += __shfl_down(a4, off, 4);
    }
    if (sub != 0 || node >= N) return;
    float rd = 1.0f / fmaxf((float)dg, 1.0f);
    float ni[F_IN] = { a0 * rd, a1 * rd, a2 * rd, a3 * rd, a4 * rd };
    float xi[F_IN];
    const float* xr = x + (size_t)node * 5;
    #pragma unroll
    for (int f = 0; f < F_IN; ++f) xi[f] = xr[f];
    unsigned short hu[8];
    #pragma unroll
    for (int j = 0; j < F_HID; ++j) {
        float acc = bias[j];
        #pragma unroll
        for (int f = 0; f < F_IN; ++f)
            acc += xi[f] * Ws[f * F_HID + j] + ni[f] * Wn[f * F_HID + j];
        hu[j] = __half_as_ushort(__float2half_rn(sigmoidf(acc)));
    }
    hu[5] = hu[6] = hu[7] = 0;
    uint4 o;
    o.x = (unsigned)hu[0] | ((unsigned)hu[1] << 16);
    o.y = (unsigned)hu[2] | ((unsigned)hu[3] << 16);
    o.z = (unsigned)hu[4] | ((unsigned)hu[5] << 16);
    o.w = 0;
    hp[node] = o;
}

// ---- layer 2: 8 lanes/node gather (one dwordx4/edge) + reduce + matmul ----
__global__ void layer2(const uint4* __restrict__ hp, const int* __restrict__ eidx,
                       const int* __restrict__ starts, const int* __restrict__ degs,
                       const float* __restrict__ Ws, const float* __restrict__ Wn,
                       const float* __restrict__ b,
                       float* __restrict__ out, int N) {
    int tid = blockIdx.x * blockDim.x + threadIdx.x;
    int v   = tid >> 3;
    int sub = threadIdx.x & (LPN2 - 1);
    if (v >= N) return;
    int st = starts[v], dg = degs[v];
    float s0 = 0, s1 = 0, s2 = 0, s3 = 0, s4 = 0;
    for (int k = sub; k < dg; k += LPN2) {
        int u = eidx[st + k];
        uint4 q = hp[u];
        float2 f01 = __half22float2(*(const __half2*)&q.x);
        float2 f23 = __half22float2(*(const __half2*)&q.y);
        float2 f45 = __half22float2(*(const __half2*)&q.z);
        s0 += f01.x; s1 += f01.y; s2 += f23.x; s3 += f23.y; s4 += f45.x;
    }
    #pragma unroll
    for (int off = LPN2 / 2; off > 0; off >>= 1) {
        s0 += __shfl_down(s0, off, LPN2);
        s1 += __shfl_down(s1, off, LPN2);
        s2 += __shfl_down(s2, off, LPN2);
        s3 += __shfl_down(s3, off, LPN2);
        s4 += __shfl_down(s4, off, LPN2);
    }
    if (sub != 0) return;
    float rd = 1.0f / fmaxf((float)dg, 1.0f);
    float ni[F_HID] = { s0 * rd, s1 * rd, s2 * rd, s3 * rd, s4 * rd };
    uint4 q = hp[v];
    float2 f01 = __half22float2(*(const __half2*)&q.x);
    float2 f23 = __half22float2(*(const __half2*)&q.y);
    float2 f45 = __half22float2(*(const __half2*)&q.z);
    float hi[F_HID] = { f01.x, f01.y, f23.x, f23.y, f45.x };
    #pragma unroll
    for (int j = 0; j < F_OUT; ++j) {
        float acc = b[j];
        #pragma unroll
        for (int f = 0; f < F_HID; ++f)
            acc += hi[f] * Ws[f * F_OUT + j] + ni[f] * Wn[f * F_OUT + j];
        out[(size_t)v * F_OUT + j] = sigmoidf(acc);
    }
}

extern "C" void kernel_launch(void* const* d_in, const int* in_sizes, int n_in,
                              void* d_out, int out_size, void* d_ws, size_t ws_size,
                              hipStream_t stream) {
    const float* x   = (const float*)d_in[0];
    const int*   src = (const int*)d_in[1];
    const int*   dst = (const int*)d_in[2];
    const float* Ws1 = (const float*)d_in[3];
    const float* Wn1 = (const float*)d_in[4];
    const float* b1  = (const float*)d_in[5];
    const float* Ws2 = (const float*)d_in[6];
    const float* Wn2 = (const float*)d_in[7];
    const float* b2  = (const float*)d_in[8];
    float* out = (float*)d_out;

    const int N  = in_sizes[0] / F_IN;        // 100000
    const int E  = in_sizes[1];               // 6400000
    const int NB = (N + NPB - 1) >> NBSHIFT;  // 782

    // workspace (4B units):
    // bcursor[1024] | starts[N] | degs[N] | packed[NB*BSTRIDE] | hp[4N uint]
    int*   bcursor = (int*)d_ws;
    int*   starts  = bcursor + 1024;
    int*   degs    = starts + N;
    int*   packed  = degs + N;
    uint4* hp      = (uint4*)(packed + (size_t)NB * BSTRIDE);

    const int ablocks = (E + CHUNK - 1) / CHUNK;              // 782
    const int lgrid   = ((size_t)N * LPN2 + LBLK - 1) / LBLK; // 3125

    init_cursors<<<1, 1024, 0, stream>>>(bcursor, NB);
    partition<<<ablocks, PBLK, 0, stream>>>(src, dst, bcursor, packed, E, NB);
    sortagg1<<<NB, SBLK, 0, stream>>>(x, packed, bcursor, Ws1, Wn1, b1,
                                      hp, starts, degs, N);
    layer2<<<lgrid, LBLK, 0, stream>>>(hp, packed, starts, degs, Ws2, Wn2, b2, out, N);
}

// Round 12
// 209.672 us; speedup vs baseline: 1.1939x; 1.0424x over previous
//
#include <hip/hip_runtime.h>
#include <hip/hip_fp16.h>
#include <math.h>

// GraphSAGE mean, 2 layers. F_IN=5, F_HID=5, F_OUT=10.
// R12 = R10 (best passing, 218us) + three fixes:
//  - x pre-converted to fp16 uint4 rows (16B): sortagg1 phase-4 gather is ONE
//    dwordx4/edge (was float4+scalar = 2 vmem instrs/edge, the issue bound).
//  - wave-shuffle scans in partition & sortagg1 (2-3 barriers, was ~20).
//  - init_cursors merged into prep.
// R11 lesson: cooperative launch failed silently -> stay multi-kernel.

#define F_IN  5
#define F_HID 5
#define F_OUT 10

#define NBSHIFT 7                 // nodes per bucket = 128
#define NPB     (1 << NBSHIFT)    // 128
#define PBLK    1024              // partition block size
#define CHUNK   8192              // edges per partition block -> run len ~10.5
#define EPT     8                 // edges per thread in partition
#define BSTRIDE 9216              // bucket stride: mean 8192 + ~11 sigma; 18*512
#define SBLK    512               // sortagg1 block size (4 lanes/node * 128)
#define SPT     18                // staged entries/thread = BSTRIDE/SBLK
#define LPN2    8                 // lanes per node in layer2
#define LBLK    256               // layer2 block size

__device__ __forceinline__ float sigmoidf(float v) {
    return 1.0f / (1.0f + __expf(-v));
}

// ---- prep: x -> fp16 uint4 rows; also init bucket cursors ----
__global__ void prep(const float* __restrict__ x, uint4* __restrict__ xh,
                     int* __restrict__ bcursor, int N, int NB) {
    int v = blockIdx.x * blockDim.x + threadIdx.x;
    if (v < NB) bcursor[v] = v * BSTRIDE;
    if (v >= N) return;
    const float* xr = x + (size_t)v * 5;
    float4 a = *(const float4*)xr;
    float a4 = xr[4];
    unsigned short h0 = __half_as_ushort(__float2half_rn(a.x));
    unsigned short h1 = __half_as_ushort(__float2half_rn(a.y));
    unsigned short h2 = __half_as_ushort(__float2half_rn(a.z));
    unsigned short h3 = __half_as_ushort(__float2half_rn(a.w));
    unsigned short h4 = __half_as_ushort(__float2half_rn(a4));
    uint4 o;
    o.x = (unsigned)h0 | ((unsigned)h1 << 16);
    o.y = (unsigned)h2 | ((unsigned)h3 << 16);
    o.z = (unsigned)h4;
    o.w = 0;
    xh[v] = o;
}

// ---- partition edges into padded bucket regions (cursor-first, 1 atomic/edge) ----
__global__ void partition(const int* __restrict__ src, const int* __restrict__ dst,
                          int* __restrict__ bcursor, int* __restrict__ packed,
                          int E, int NB) {
    __shared__ int cnt[PBLK], excl[PBLK], adj[PBLK];
    __shared__ int wsum[16];
    __shared__ int buf[CHUNK];
    __shared__ unsigned char dlow[CHUNK];
    int t = threadIdx.x;
    int lane = t & 63, w = t >> 6;
    cnt[t] = 0;
    __syncthreads();
    int base = blockIdx.x * CHUNK;
    int end  = min(base + CHUNK, E);
    // phase 1: load edges to registers, rank via single LDS cursor atomic
    int esd[EPT];   // src | dlow<<17
    int ebp[EPT];   // b<<14 | p   (p < 8192)
    #pragma unroll
    for (int j = 0; j < EPT; ++j) {
        int i = base + t + j * PBLK;
        if (i < end) {
            int sv = src[i], d = dst[i];
            int b  = d >> NBSHIFT;
            int p  = atomicAdd(&cnt[b], 1);
            esd[j] = sv | ((d & (NPB - 1)) << 17);
            ebp[j] = (b << 14) | p;
        }
    }
    __syncthreads();
    // wave-shuffle inclusive scan of cnt[0..PBLK)
    int v = cnt[t];
    int incl = v;
    #pragma unroll
    for (int off = 1; off < 64; off <<= 1) {
        int u = __shfl_up(incl, off, 64);
        if (lane >= off) incl += u;
    }
    if (lane == 63) wsum[w] = incl;
    __syncthreads();
    if (t < 16) {
        int s = wsum[t];
        #pragma unroll
        for (int off = 1; off < 16; off <<= 1) {
            int u = __shfl_up(s, off, 16);
            if (t >= off) s += u;
        }
        wsum[t] = s;
    }
    __syncthreads();
    int wbase = (w > 0) ? wsum[w - 1] : 0;
    excl[t] = incl - v + wbase;
    __syncthreads();
    // reserve global space per bucket; adj[b] = goff - excl[b]
    if (t < NB) {
        int cb = cnt[t];
        int go = cb ? atomicAdd(&bcursor[t], cb) : 0;
        adj[t] = go - excl[t];
    }
    __syncthreads();
    // phase 2: place from registers into LDS, bucket-grouped (plain writes)
    #pragma unroll
    for (int j = 0; j < EPT; ++j) {
        int i = base + t + j * PBLK;
        if (i < end) {
            int b   = ebp[j] >> 14;
            int pos = excl[b] + (ebp[j] & 0x3FFF);
            buf[pos]  = (esd[j] & 0x1FFFF) | (b << 17);
            dlow[pos] = (unsigned char)(esd[j] >> 17);
        }
    }
    __syncthreads();
    // phase 3: write runs out (consecutive pos -> same bucket -> coalesced)
    int cval = end - base;
    for (int p = t; p < cval; p += PBLK) {
        int e = buf[p];
        int b = e >> 17;
        packed[adj[b] + p] = (e & 0x1FFFF) | ((int)dlow[p] << 17);
    }
}

// ---- fused: per-bucket counting sort (cursor-first) + layer-1 ----
// Writes sorted eidx back (in place), starts[], degs[], hp as half[8] rows.
__global__ void __launch_bounds__(SBLK, 8)
sortagg1(const uint4* __restrict__ xh, int* __restrict__ packed,
         const int* __restrict__ bcursor,
         const float* __restrict__ Ws, const float* __restrict__ Wn,
         const float* __restrict__ bias,
         uint4* __restrict__ hp, int* __restrict__ starts,
         int* __restrict__ degs, int N) {
    __shared__ int buf[BSTRIDE];
    __shared__ int ncnt[NPB], nst[NPB];
    __shared__ int w0sum;
    int b = blockIdx.x, t = threadIdx.x;
    int s0  = b * BSTRIDE;
    int cnt = min(bcursor[b] - s0, BSTRIDE);
    if (t < NPB) ncnt[t] = 0;
    __syncthreads();
    // phase 1: stage entries in registers, rank via single LDS cursor atomic
    int myv[SPT];
    short myp[SPT];
    #pragma unroll
    for (int j = 0; j < SPT; ++j) {
        int i = t + j * SBLK;
        if (i < cnt) {
            int e = packed[s0 + i];
            myv[j] = e;
            myp[j] = (short)atomicAdd(&ncnt[(e >> 17) & (NPB - 1)], 1);
        }
    }
    __syncthreads();
    // wave-shuffle exclusive scan of 128 bins (threads 0..127 = 2 waves)
    if (t < NPB) {
        int lane = t & 63;
        int v = ncnt[t];
        int incl = v;
        #pragma unroll
        for (int off = 1; off < 64; off <<= 1) {
            int u = __shfl_up(incl, off, 64);
            if (lane >= off) incl += u;
        }
        if (t == 63) w0sum = incl;
        nst[t] = incl - v;   // missing wave-1 base, fixed below
    }
    __syncthreads();
    if (t >= 64 && t < NPB) nst[t] += w0sum;
    __syncthreads();
    if (t < NPB) {
        int node = (b << NBSHIFT) + t;
        if (node < N) { starts[node] = s0 + nst[t]; degs[node] = ncnt[t]; }
    }
    __syncthreads();
    // phase 2: place sorted into LDS from registers (plain writes)
    #pragma unroll
    for (int j = 0; j < SPT; ++j) {
        int i = t + j * SBLK;
        if (i < cnt) {
            int e = myv[j];
            buf[nst[(e >> 17) & (NPB - 1)] + (int)myp[j]] = e;
        }
    }
    __syncthreads();
    // phase 3: write sorted eidx back for layer2
    for (int i = t; i < cnt; i += SBLK)
        packed[s0 + i] = buf[i] & 0x1FFFF;
    // phase 4: layer-1 aggregation from LDS, 4 lanes/node, ONE dwordx4/edge
    int sub = t & 3, ln = t >> 2;          // ln in [0,128)
    int node = (b << NBSHIFT) + ln;
    float a0 = 0, a1 = 0, a2 = 0, a3 = 0, a4 = 0;
    int dg = 0;
    if (node < N) {
        int st = nst[ln];
        dg = ncnt[ln];
        for (int k = sub; k < dg; k += 4) {
            int u = buf[st + k] & 0x1FFFF;
            uint4 q = xh[u];
            float2 f01 = __half22float2(*(const __half2*)&q.x);
            float2 f23 = __half22float2(*(const __half2*)&q.y);
            float2 f45 = __half22float2(*(const __half2*)&q.z);
            a0 += f01.x; a1 += f01.y; a2 += f23.x; a3 += f23.y; a4 += f45.x;
        }
    }
    #pragma unroll
    for (int off = 2; off > 0; off >>= 1) {
        a0 += __shfl_down(a0, off, 4);
        a1 += __shfl_down(a1, off, 4);
        a2 += __shfl_down(a2, off, 4);
        a3 += __shfl_down(a3, off, 4);
        a4 += __shfl_down(a4, off, 4);
    }
    if (sub != 0 || node >= N) return;
    float rd = 1.0f / fmaxf((float)dg, 1.0f);
    float ni[F_IN] = { a0 * rd, a1 * rd, a2 * rd, a3 * rd, a4 * rd };
    uint4 qs = xh[node];
    float2 s01 = __half22float2(*(const __half2*)&qs.x);
    float2 s23 = __half22float2(*(const __half2*)&qs.y);
    float2 s45 = __half22float2(*(const __half2*)&qs.z);
    float xi[F_IN] = { s01.x, s01.y, s23.x, s23.y, s45.x };
    unsigned short hu[6];
    #pragma unroll
    for (int j = 0; j < F_HID; ++j) {
        float acc = bias[j];
        #pragma unroll
        for (int f = 0; f < F_IN; ++f)
            acc += xi[f] * Ws[f * F_HID + j] + ni[f] * Wn[f * F_HID + j];
        hu[j] = __half_as_ushort(__float2half_rn(sigmoidf(acc)));
    }
    hu[5] = 0;
    uint4 o;
    o.x = (unsigned)hu[0] | ((unsigned)hu[1] << 16);
    o.y = (unsigned)hu[2] | ((unsigned)hu[3] << 16);
    o.z = (unsigned)hu[4];
    o.w = 0;
    hp[node] = o;
}

// ---- layer 2: 8 lanes/node gather (one dwordx4/edge) + reduce + matmul ----
__global__ void layer2(const uint4* __restrict__ hp, const int* __restrict__ eidx,
                       const int* __restrict__ starts, const int* __restrict__ degs,
                       const float* __restrict__ Ws, const float* __restrict__ Wn,
                       const float* __restrict__ b,
                       float* __restrict__ out, int N) {
    int tid = blockIdx.x * blockDim.x + threadIdx.x;
    int v   = tid >> 3;
    int sub = threadIdx.x & (LPN2 - 1);
    if (v >= N) return;
    int st = starts[v], dg = degs[v];
    float s0 = 0, s1 = 0, s2 = 0, s3 = 0, s4 = 0;
    for (int k = sub; k < dg; k += LPN2) {
        int u = eidx[st + k];
        uint4 q = hp[u];
        float2 f01 = __half22float2(*(const __half2*)&q.x);
        float2 f23 = __half22float2(*(const __half2*)&q.y);
        float2 f45 = __half22float2(*(const __half2*)&q.z);
        s0 += f01.x; s1 += f01.y; s2 += f23.x; s3 += f23.y; s4 += f45.x;
    }
    #pragma unroll
    for (int off = LPN2 / 2; off > 0; off >>= 1) {
        s0 += __shfl_down(s0, off, LPN2);
        s1 += __shfl_down(s1, off, LPN2);
        s2 += __shfl_down(s2, off, LPN2);
        s3 += __shfl_down(s3, off, LPN2);
        s4 += __shfl_down(s4, off, LPN2);
    }
    if (sub != 0) return;
    float rd = 1.0f / fmaxf((float)dg, 1.0f);
    float ni[F_HID] = { s0 * rd, s1 * rd, s2 * rd, s3 * rd, s4 * rd };
    uint4 q = hp[v];
    float2 f01 = __half22float2(*(const __half2*)&q.x);
    float2 f23 = __half22float2(*(const __half2*)&q.y);
    float2 f45 = __half22float2(*(const __half2*)&q.z);
    float hi[F_HID] = { f01.x, f01.y, f23.x, f23.y, f45.x };
    #pragma unroll
    for (int j = 0; j < F_OUT; ++j) {
        float acc = b[j];
        #pragma unroll
        for (int f = 0; f < F_HID; ++f)
            acc += hi[f] * Ws[f * F_OUT + j] + ni[f] * Wn[f * F_OUT + j];
        out[(size_t)v * F_OUT + j] = sigmoidf(acc);
    }
}

extern "C" void kernel_launch(void* const* d_in, const int* in_sizes, int n_in,
                              void* d_out, int out_size, void* d_ws, size_t ws_size,
                              hipStream_t stream) {
    const float* x   = (const float*)d_in[0];
    const int*   src = (const int*)d_in[1];
    const int*   dst = (const int*)d_in[2];
    const float* Ws1 = (const float*)d_in[3];
    const float* Wn1 = (const float*)d_in[4];
    const float* b1  = (const float*)d_in[5];
    const float* Ws2 = (const float*)d_in[6];
    const float* Wn2 = (const float*)d_in[7];
    const float* b2  = (const float*)d_in[8];
    float* out = (float*)d_out;

    const int N  = in_sizes[0] / F_IN;        // 100000
    const int E  = in_sizes[1];               // 6400000
    const int NB = (N + NPB - 1) >> NBSHIFT;  // 782

    // workspace (4B units):
    // bcursor[1024] | xh[4N] | starts[N] | degs[N] | packed[NB*BSTRIDE] | hp[4N]
    int*   bcursor = (int*)d_ws;
    uint4* xh      = (uint4*)(bcursor + 1024);
    int*   starts  = (int*)(xh + N);
    int*   degs    = starts + N;
    int*   packed  = degs + N;
    uint4* hp      = (uint4*)(packed + (size_t)NB * BSTRIDE);

    const int ablocks = (E + CHUNK - 1) / CHUNK;              // 782
    const int pgrid   = (N + 255) / 256;                      // 391 (covers NB)
    const int lgrid   = ((size_t)N * LPN2 + LBLK - 1) / LBLK; // 3125

    prep<<<pgrid, 256, 0, stream>>>(x, xh, bcursor, N, NB);
    partition<<<ablocks, PBLK, 0, stream>>>(src, dst, bcursor, packed, E, NB);
    sortagg1<<<NB, SBLK, 0, stream>>>(xh, packed, bcursor, Ws1, Wn1, b1,
                                      hp, starts, degs, N);
    layer2<<<lgrid, LBLK, 0, stream>>>(hp, packed, starts, degs, Ws2, Wn2, b2, out, N);
}